// Round 1
// baseline (1330.995 us; speedup 1.0000x reference)
//
#include <hip/hip_runtime.h>
#include <math.h>

#define TB 256

// ---------------- degree / norm ----------------
__global__ void k_deg_init(float* __restrict__ deg, int n) {
    int i = blockIdx.x * TB + threadIdx.x;
    if (i < n) deg[i] = 1.0f;  // self-loop
}

__global__ void k_deg_count(const int* __restrict__ col, float* __restrict__ deg, int E) {
    int e = blockIdx.x * TB + threadIdx.x;
    if (e < E) atomicAdd(&deg[col[e]], 1.0f);
}

__global__ void k_dinv(float* __restrict__ deg, int n) {
    int i = blockIdx.x * TB + threadIdx.x;
    if (i < n) deg[i] = rsqrtf(deg[i]);  // deg >= 1 always (self loop)
}

// ---------------- layer-1 GEMM: sxw = acc = dinv[n] * (x @ W1) ----------------
// x: [n,512] f32, W1: [512,16] row-major. 4 threads per node, each owns 4 output cols.
__global__ void k_gemm1(const float* __restrict__ x, const float* __restrict__ W1,
                        const float* __restrict__ dinv, float* __restrict__ sxw,
                        float* __restrict__ acc, int n) {
    __shared__ float4 sW[2048];  // W1 as float4: sW[k*4+q] = W1[k][4q..4q+3], 32 KB
    const float4* w4 = (const float4*)W1;
    for (int p = threadIdx.x; p < 2048; p += TB) sW[p] = w4[p];
    __syncthreads();

    int idx  = blockIdx.x * TB + threadIdx.x;
    int node = idx >> 2, q = idx & 3;
    if (node >= n) return;

    const float4* xr = (const float4*)(x + (size_t)node * 512);
    float ax = 0.f, ay = 0.f, az = 0.f, aw = 0.f;
#pragma unroll 4
    for (int kk = 0; kk < 128; ++kk) {
        float4 xv  = xr[kk];
        float4 w0  = sW[(4 * kk + 0) * 4 + q];
        float4 w1v = sW[(4 * kk + 1) * 4 + q];
        float4 w2v = sW[(4 * kk + 2) * 4 + q];
        float4 w3v = sW[(4 * kk + 3) * 4 + q];
        ax = fmaf(xv.x, w0.x, ax);  ay = fmaf(xv.x, w0.y, ay);
        az = fmaf(xv.x, w0.z, az);  aw = fmaf(xv.x, w0.w, aw);
        ax = fmaf(xv.y, w1v.x, ax); ay = fmaf(xv.y, w1v.y, ay);
        az = fmaf(xv.y, w1v.z, az); aw = fmaf(xv.y, w1v.w, aw);
        ax = fmaf(xv.z, w2v.x, ax); ay = fmaf(xv.z, w2v.y, ay);
        az = fmaf(xv.z, w2v.z, az); aw = fmaf(xv.z, w2v.w, aw);
        ax = fmaf(xv.w, w3v.x, ax); ay = fmaf(xv.w, w3v.y, ay);
        az = fmaf(xv.w, w3v.z, az); aw = fmaf(xv.w, w3v.w, aw);
    }
    float s = dinv[node];
    float4 r;
    r.x = ax * s; r.y = ay * s; r.z = az * s; r.w = aw * s;
    ((float4*)sxw)[idx] = r;  // idx == node*4+q
    ((float4*)acc)[idx] = r;  // acc init = self-loop contribution
}

// ---------------- layer-1 scatter: acc[col] += sxw[row], 4 threads/edge ----------------
__global__ void k_scatter1(const int* __restrict__ row, const int* __restrict__ col,
                           const float* __restrict__ sxw, float* __restrict__ acc, int E) {
    int idx = blockIdx.x * TB + threadIdx.x;
    int e = idx >> 2, q = idx & 3;
    if (e >= E) return;
    int r = row[e], c = col[e];
    float4 v = ((const float4*)sxw)[r * 4 + q];
    float* dst = acc + (size_t)c * 16 + q * 4;
    atomicAdd(dst + 0, v.x);
    atomicAdd(dst + 1, v.y);
    atomicAdd(dst + 2, v.z);
    atomicAdd(dst + 3, v.w);
}

// ---------------- finalize layer 1 + layer-2 GEMM ----------------
// h1 = relu(dinv*acc1 + b1); sxw2 = acc2 = dinv * (h1 @ W2)
__global__ void k_fin1(const float* __restrict__ acc1, const float* __restrict__ dinv,
                       const float* __restrict__ W2, const float* __restrict__ b1,
                       float* __restrict__ sxw2, float* __restrict__ acc2, int n) {
    __shared__ float sW2[112];  // [16][7]
    __shared__ float sb1[16];
    if (threadIdx.x < 112) sW2[threadIdx.x] = W2[threadIdx.x];
    if (threadIdx.x < 16) sb1[threadIdx.x] = b1[threadIdx.x];
    __syncthreads();

    int i = blockIdx.x * TB + threadIdx.x;
    if (i >= n) return;
    float s = dinv[i];

    float h[16];
    const float4* a4 = (const float4*)(acc1 + (size_t)i * 16);
#pragma unroll
    for (int q = 0; q < 4; ++q) {
        float4 v = a4[q];
        h[4 * q + 0] = fmaxf(fmaf(s, v.x, sb1[4 * q + 0]), 0.f);
        h[4 * q + 1] = fmaxf(fmaf(s, v.y, sb1[4 * q + 1]), 0.f);
        h[4 * q + 2] = fmaxf(fmaf(s, v.z, sb1[4 * q + 2]), 0.f);
        h[4 * q + 3] = fmaxf(fmaf(s, v.w, sb1[4 * q + 3]), 0.f);
    }
    float o[7] = {0.f, 0.f, 0.f, 0.f, 0.f, 0.f, 0.f};
#pragma unroll
    for (int k = 0; k < 16; ++k) {
        float hk = h[k];
#pragma unroll
        for (int j = 0; j < 7; ++j) o[j] = fmaf(hk, sW2[k * 7 + j], o[j]);
    }
    size_t base = (size_t)i * 7;
#pragma unroll
    for (int j = 0; j < 7; ++j) {
        float v = o[j] * s;
        sxw2[base + j] = v;
        acc2[base + j] = v;
    }
}

// ---------------- layer-2 scatter: 8 threads/edge (7 active) ----------------
__global__ void k_scatter2(const int* __restrict__ row, const int* __restrict__ col,
                           const float* __restrict__ sxw2, float* __restrict__ acc2, int E) {
    int idx = blockIdx.x * TB + threadIdx.x;
    int e = idx >> 3, q = idx & 7;
    if (e >= E || q >= 7) return;
    int r = row[e], c = col[e];
    atomicAdd(acc2 + (size_t)c * 7 + q, sxw2[(size_t)r * 7 + q]);
}

// ---------------- finalize layer 2 + log_softmax ----------------
__global__ void k_fin2(const float* __restrict__ acc2, const float* __restrict__ dinv,
                       const float* __restrict__ b2, float* __restrict__ out, int n) {
    int i = blockIdx.x * TB + threadIdx.x;
    if (i >= n) return;
    float s = dinv[i];
    size_t base = (size_t)i * 7;
    float z[7];
    float m = -INFINITY;
#pragma unroll
    for (int j = 0; j < 7; ++j) {
        z[j] = fmaf(s, acc2[base + j], b2[j]);
        m = fmaxf(m, z[j]);
    }
    float sum = 0.f;
#pragma unroll
    for (int j = 0; j < 7; ++j) sum += expf(z[j] - m);
    float l = m + logf(sum);
#pragma unroll
    for (int j = 0; j < 7; ++j) out[base + j] = z[j] - l;
}

extern "C" void kernel_launch(void* const* d_in, const int* in_sizes, int n_in,
                              void* d_out, int out_size, void* d_ws, size_t ws_size,
                              hipStream_t stream) {
    const float* x  = (const float*)d_in[0];
    const int*   ei = (const int*)d_in[1];
    const float* W1 = (const float*)d_in[2];
    const float* b1 = (const float*)d_in[3];
    const float* W2 = (const float*)d_in[4];
    const float* b2 = (const float*)d_in[5];

    int N = in_sizes[0] / 512;  // 100000
    int E = in_sizes[1] / 2;    // 3200000
    const int* row = ei;        // sources
    const int* col = ei + E;    // targets

    float* ws   = (float*)d_ws;
    float* deg  = ws;                       // N   (becomes dinv in-place)
    float* sxw1 = deg + N;                  // 16N
    float* acc1 = sxw1 + (size_t)16 * N;    // 16N
    float* sxw2 = acc1 + (size_t)16 * N;    // 7N
    float* acc2 = sxw2 + (size_t)7 * N;     // 7N
    float* out  = (float*)d_out;

    int gN = (N + TB - 1) / TB;
    k_deg_init<<<gN, TB, 0, stream>>>(deg, N);
    k_deg_count<<<(E + TB - 1) / TB, TB, 0, stream>>>(col, deg, E);
    k_dinv<<<gN, TB, 0, stream>>>(deg, N);
    k_gemm1<<<(4 * N + TB - 1) / TB, TB, 0, stream>>>(x, W1, deg, sxw1, acc1, N);
    k_scatter1<<<(4 * E + TB - 1) / TB, TB, 0, stream>>>(row, col, sxw1, acc1, E);
    k_fin1<<<gN, TB, 0, stream>>>(acc1, deg, W2, b1, sxw2, acc2, N);
    k_scatter2<<<(8 * E + TB - 1) / TB, TB, 0, stream>>>(row, col, sxw2, acc2, E);
    k_fin2<<<gN, TB, 0, stream>>>(acc2, deg, b2, out, N);
}

// Round 2
// 1091.682 us; speedup vs baseline: 1.2192x; 1.2192x over previous
//
#include <hip/hip_runtime.h>
#include <math.h>
#include <stdint.h>

#define TB 256
#define SCAN_T 1024

// ---------------- zero int degree array ----------------
__global__ void k_zero(int* __restrict__ p, int n) {
    int i = blockIdx.x * TB + threadIdx.x;
    if (i < n) p[i] = 0;
}

// ---------------- int degree histogram (in-degree, targets) ----------------
__global__ void k_count(const int* __restrict__ col, int* __restrict__ degi, int E) {
    int e = blockIdx.x * TB + threadIdx.x;
    if (e < E) atomicAdd(&degi[col[e]], 1);
}

// ---------------- single-block scan: offsets (exclusive), cursor copy, dinv ----------------
__global__ void k_scan(const int* __restrict__ degi, int* __restrict__ offs,
                       int* __restrict__ cursor, float* __restrict__ dinv, int n, int E) {
    __shared__ int s[SCAN_T];
    int t = threadIdx.x;
    int chunk = (n + SCAN_T - 1) / SCAN_T;
    int beg = t * chunk, end = min(beg + chunk, n);
    int sum = 0;
    for (int i = beg; i < end; ++i) sum += degi[i];
    s[t] = sum;
    __syncthreads();
    for (int off = 1; off < SCAN_T; off <<= 1) {
        int v = (t >= off) ? s[t - off] : 0;
        __syncthreads();
        s[t] += v;
        __syncthreads();
    }
    int run = (t == 0) ? 0 : s[t - 1];  // exclusive prefix of this thread's chunk
    for (int i = beg; i < end; ++i) {
        int d = degi[i];
        offs[i] = run;
        cursor[i] = run;
        dinv[i] = rsqrtf((float)(d + 1));  // +1 = self-loop
        run += d;
    }
    if (t == 0) offs[n] = E;
}

// ---------------- counting-sort placement: srow holds sources grouped by target ----------------
__global__ void k_sort(const int* __restrict__ row, const int* __restrict__ col,
                       int* __restrict__ cursor, int* __restrict__ srow, int E) {
    int e = blockIdx.x * TB + threadIdx.x;
    if (e >= E) return;
    int c = col[e];
    int pos = atomicAdd(&cursor[c], 1);
    srow[pos] = row[e];
}

// ---------------- layer-1 GEMM: sxw1 = dinv[n] * (x @ W1) ----------------
// 4 threads per node, each owns 4 output cols.
__global__ void k_gemm1(const float* __restrict__ x, const float* __restrict__ W1,
                        const float* __restrict__ dinv, float* __restrict__ sxw, int n) {
    __shared__ float4 sW[2048];  // W1 as float4: sW[k*4+q] = W1[k][4q..4q+3]
    const float4* w4 = (const float4*)W1;
    for (int p = threadIdx.x; p < 2048; p += TB) sW[p] = w4[p];
    __syncthreads();

    int idx  = blockIdx.x * TB + threadIdx.x;
    int node = idx >> 2, q = idx & 3;
    if (node >= n) return;

    const float4* xr = (const float4*)(x + (size_t)node * 512);
    float ax = 0.f, ay = 0.f, az = 0.f, aw = 0.f;
#pragma unroll 4
    for (int kk = 0; kk < 128; ++kk) {
        float4 xv  = xr[kk];
        float4 w0  = sW[(4 * kk + 0) * 4 + q];
        float4 w1v = sW[(4 * kk + 1) * 4 + q];
        float4 w2v = sW[(4 * kk + 2) * 4 + q];
        float4 w3v = sW[(4 * kk + 3) * 4 + q];
        ax = fmaf(xv.x, w0.x, ax);  ay = fmaf(xv.x, w0.y, ay);
        az = fmaf(xv.x, w0.z, az);  aw = fmaf(xv.x, w0.w, aw);
        ax = fmaf(xv.y, w1v.x, ax); ay = fmaf(xv.y, w1v.y, ay);
        az = fmaf(xv.y, w1v.z, az); aw = fmaf(xv.y, w1v.w, aw);
        ax = fmaf(xv.z, w2v.x, ax); ay = fmaf(xv.z, w2v.y, ay);
        az = fmaf(xv.z, w2v.z, az); aw = fmaf(xv.z, w2v.w, aw);
        ax = fmaf(xv.w, w3v.x, ax); ay = fmaf(xv.w, w3v.y, ay);
        az = fmaf(xv.w, w3v.z, az); aw = fmaf(xv.w, w3v.w, aw);
    }
    float s = dinv[node];
    float4 r;
    r.x = ax * s; r.y = ay * s; r.z = az * s; r.w = aw * s;
    ((float4*)sxw)[idx] = r;
}

// ---------------- layer-1 gather: acc1[c] = sxw1[c] + sum_{r in in(c)} sxw1[r] ----------------
// 4 lanes per node (consecutive), each owns a float4 column slice -> 64 B coalesced per edge.
__global__ void k_gather1(const int* __restrict__ offs, const int* __restrict__ srow,
                          const float* __restrict__ sxw, float* __restrict__ acc, int n) {
    int idx  = blockIdx.x * TB + threadIdx.x;
    int node = idx >> 2, q = idx & 3;
    if (node >= n) return;
    const float4* s4 = (const float4*)sxw;
    int beg = offs[node], end = offs[node + 1];
    float4 a = s4[node * 4 + q];  // self-loop
    int j = beg;
    for (; j + 1 < end; j += 2) {
        int r0 = srow[j], r1 = srow[j + 1];
        float4 v0 = s4[r0 * 4 + q];
        float4 v1 = s4[r1 * 4 + q];
        a.x += v0.x + v1.x; a.y += v0.y + v1.y;
        a.z += v0.z + v1.z; a.w += v0.w + v1.w;
    }
    if (j < end) {
        int r0 = srow[j];
        float4 v0 = s4[r0 * 4 + q];
        a.x += v0.x; a.y += v0.y; a.z += v0.z; a.w += v0.w;
    }
    ((float4*)acc)[node * 4 + q] = a;
}

// ---------------- finalize layer 1 + layer-2 GEMM -> sxw2 padded to [N,8] ----------------
__global__ void k_fin1(const float* __restrict__ acc1, const float* __restrict__ dinv,
                       const float* __restrict__ W2, const float* __restrict__ b1,
                       float* __restrict__ sxw2p, int n) {
    __shared__ float sW2[112];  // [16][7]
    __shared__ float sb1[16];
    if (threadIdx.x < 112) sW2[threadIdx.x] = W2[threadIdx.x];
    if (threadIdx.x < 16) sb1[threadIdx.x] = b1[threadIdx.x];
    __syncthreads();

    int i = blockIdx.x * TB + threadIdx.x;
    if (i >= n) return;
    float s = dinv[i];

    float h[16];
    const float4* a4 = (const float4*)(acc1 + (size_t)i * 16);
#pragma unroll
    for (int q = 0; q < 4; ++q) {
        float4 v = a4[q];
        h[4 * q + 0] = fmaxf(fmaf(s, v.x, sb1[4 * q + 0]), 0.f);
        h[4 * q + 1] = fmaxf(fmaf(s, v.y, sb1[4 * q + 1]), 0.f);
        h[4 * q + 2] = fmaxf(fmaf(s, v.z, sb1[4 * q + 2]), 0.f);
        h[4 * q + 3] = fmaxf(fmaf(s, v.w, sb1[4 * q + 3]), 0.f);
    }
    float o[8] = {0.f, 0.f, 0.f, 0.f, 0.f, 0.f, 0.f, 0.f};
#pragma unroll
    for (int k = 0; k < 16; ++k) {
        float hk = h[k];
#pragma unroll
        for (int j = 0; j < 7; ++j) o[j] = fmaf(hk, sW2[k * 7 + j], o[j]);
    }
    float4* dst = (float4*)(sxw2p + (size_t)i * 8);
    float4 lo, hi;
    lo.x = o[0] * s; lo.y = o[1] * s; lo.z = o[2] * s; lo.w = o[3] * s;
    hi.x = o[4] * s; hi.y = o[5] * s; hi.z = o[6] * s; hi.w = 0.f;
    dst[0] = lo; dst[1] = hi;
}

// ---------------- layer-2 gather on padded [N,8]: 2 lanes per node ----------------
__global__ void k_gather2(const int* __restrict__ offs, const int* __restrict__ srow,
                          const float* __restrict__ sxw2p, float* __restrict__ acc2p, int n) {
    int idx  = blockIdx.x * TB + threadIdx.x;
    int node = idx >> 1, q = idx & 1;
    if (node >= n) return;
    const float4* s4 = (const float4*)sxw2p;
    int beg = offs[node], end = offs[node + 1];
    float4 a = s4[node * 2 + q];  // self-loop
    int j = beg;
    for (; j + 1 < end; j += 2) {
        int r0 = srow[j], r1 = srow[j + 1];
        float4 v0 = s4[r0 * 2 + q];
        float4 v1 = s4[r1 * 2 + q];
        a.x += v0.x + v1.x; a.y += v0.y + v1.y;
        a.z += v0.z + v1.z; a.w += v0.w + v1.w;
    }
    if (j < end) {
        int r0 = srow[j];
        float4 v0 = s4[r0 * 2 + q];
        a.x += v0.x; a.y += v0.y; a.z += v0.z; a.w += v0.w;
    }
    ((float4*)acc2p)[node * 2 + q] = a;
}

// ---------------- finalize layer 2 + log_softmax ----------------
__global__ void k_fin2(const float* __restrict__ acc2p, const float* __restrict__ dinv,
                       const float* __restrict__ b2, float* __restrict__ out, int n) {
    int i = blockIdx.x * TB + threadIdx.x;
    if (i >= n) return;
    float s = dinv[i];
    const float* a = acc2p + (size_t)i * 8;
    float z[7];
    float m = -INFINITY;
#pragma unroll
    for (int j = 0; j < 7; ++j) {
        z[j] = fmaf(s, a[j], b2[j]);
        m = fmaxf(m, z[j]);
    }
    float sum = 0.f;
#pragma unroll
    for (int j = 0; j < 7; ++j) sum += expf(z[j] - m);
    float l = m + logf(sum);
    size_t base = (size_t)i * 7;
#pragma unroll
    for (int j = 0; j < 7; ++j) out[base + j] = z[j] - l;
}

extern "C" void kernel_launch(void* const* d_in, const int* in_sizes, int n_in,
                              void* d_out, int out_size, void* d_ws, size_t ws_size,
                              hipStream_t stream) {
    const float* x  = (const float*)d_in[0];
    const int*   ei = (const int*)d_in[1];
    const float* W1 = (const float*)d_in[2];
    const float* b1 = (const float*)d_in[3];
    const float* W2 = (const float*)d_in[4];
    const float* b2 = (const float*)d_in[5];

    int N = in_sizes[0] / 512;  // 100000
    int E = in_sizes[1] / 2;    // 3200000
    const int* row = ei;        // sources
    const int* col = ei + E;    // targets

    // workspace layout
    int* degi   = (int*)d_ws;          // N
    int* offs   = degi + N;            // N+1
    int* cursor = offs + N + 1;        // N
    int* srow   = cursor + N;          // E
    uintptr_t p = (uintptr_t)(srow + E);
    p = (p + 15) & ~(uintptr_t)15;
    float* dinv = (float*)p;                  // N  (N*4 is 16B multiple)
    float* sxw1 = dinv + N;                   // 16N
    float* acc1 = sxw1 + (size_t)16 * N;      // 16N
    float* sxw2p = sxw1;                      // 8N, aliases dead sxw1
    float* acc2p = acc1;                      // 8N, aliases dead acc1
    float* out  = (float*)d_out;

    int gN = (N + TB - 1) / TB;
    int gE = (E + TB - 1) / TB;
    k_zero <<<gN, TB, 0, stream>>>(degi, N);
    k_count<<<gE, TB, 0, stream>>>(col, degi, E);
    k_scan <<<1, SCAN_T, 0, stream>>>(degi, offs, cursor, dinv, N, E);
    k_sort <<<gE, TB, 0, stream>>>(row, col, cursor, srow, E);
    k_gemm1<<<(4 * N + TB - 1) / TB, TB, 0, stream>>>(x, W1, dinv, sxw1, N);
    k_gather1<<<(4 * N + TB - 1) / TB, TB, 0, stream>>>(offs, srow, sxw1, acc1, N);
    k_fin1 <<<gN, TB, 0, stream>>>(acc1, dinv, W2, b1, sxw2p, N);
    k_gather2<<<(2 * N + TB - 1) / TB, TB, 0, stream>>>(offs, srow, sxw2p, acc2p, N);
    k_fin2 <<<gN, TB, 0, stream>>>(acc2p, dinv, b2, out, N);
}

// Round 3
// 818.227 us; speedup vs baseline: 1.6267x; 1.3342x over previous
//
#include <hip/hip_runtime.h>
#include <math.h>
#include <stdint.h>

#define TB 256
#define SCB 1024  // degree elements per scan block

// ---------------- zero int degree array ----------------
__global__ void k_zero(int* __restrict__ p, int n) {
    int i = blockIdx.x * TB + threadIdx.x;
    if (i < n) p[i] = 0;
}

// ---------------- fused: degree histogram + unscaled x@W1 ----------------
// blocks [0,cBlocks): count atomics (idle VALU); rest: GEMM (fills the VALU).
__global__ void k_count_gemm(const int* __restrict__ col, int* __restrict__ degi, int E,
                             int cBlocks, const float* __restrict__ x,
                             const float* __restrict__ W1, float* __restrict__ xw, int n) {
    __shared__ float4 sW[2048];
    if (blockIdx.x < cBlocks) {
        int e = blockIdx.x * TB + threadIdx.x;
        if (e < E) atomicAdd(&degi[col[e]], 1);
        return;
    }
    const float4* w4 = (const float4*)W1;
    for (int p = threadIdx.x; p < 2048; p += TB) sW[p] = w4[p];
    __syncthreads();

    int idx  = (blockIdx.x - cBlocks) * TB + threadIdx.x;
    int node = idx >> 2, q = idx & 3;
    if (node >= n) return;

    const float4* xr = (const float4*)(x + (size_t)node * 512);
    float ax = 0.f, ay = 0.f, az = 0.f, aw = 0.f;
#pragma unroll 4
    for (int kk = 0; kk < 128; ++kk) {
        float4 xv  = xr[kk];
        float4 w0  = sW[(4 * kk + 0) * 4 + q];
        float4 w1v = sW[(4 * kk + 1) * 4 + q];
        float4 w2v = sW[(4 * kk + 2) * 4 + q];
        float4 w3v = sW[(4 * kk + 3) * 4 + q];
        ax = fmaf(xv.x, w0.x, ax);  ay = fmaf(xv.x, w0.y, ay);
        az = fmaf(xv.x, w0.z, az);  aw = fmaf(xv.x, w0.w, aw);
        ax = fmaf(xv.y, w1v.x, ax); ay = fmaf(xv.y, w1v.y, ay);
        az = fmaf(xv.y, w1v.z, az); aw = fmaf(xv.y, w1v.w, aw);
        ax = fmaf(xv.z, w2v.x, ax); ay = fmaf(xv.z, w2v.y, ay);
        az = fmaf(xv.z, w2v.z, az); aw = fmaf(xv.z, w2v.w, aw);
        ax = fmaf(xv.w, w3v.x, ax); ay = fmaf(xv.w, w3v.y, ay);
        az = fmaf(xv.w, w3v.z, az); aw = fmaf(xv.w, w3v.w, aw);
    }
    float4 r; r.x = ax; r.y = ay; r.z = az; r.w = aw;
    ((float4*)xw)[idx] = r;
}

// ---------------- parallel scan, 3 phases ----------------
__global__ void k_scan_a(const int* __restrict__ degi, int* __restrict__ bsum, int n) {
    __shared__ int s[256];
    int t = threadIdx.x;
    int base = blockIdx.x * SCB + t * 4;
    int sum = 0;
    if (base + 3 < n) {
        int4 v = *(const int4*)(degi + base);
        sum = v.x + v.y + v.z + v.w;
    } else {
        for (int i = base; i < n && i < base + 4; ++i) sum += degi[i];
    }
    s[t] = sum;
    __syncthreads();
    for (int off = 128; off > 0; off >>= 1) {
        if (t < off) s[t] += s[t + off];
        __syncthreads();
    }
    if (t == 0) bsum[blockIdx.x] = s[0];
}

__global__ void k_scan_b(const int* __restrict__ bsum, int* __restrict__ bpre, int nB) {
    __shared__ int s[1024];
    int t = threadIdx.x;
    s[t] = (t < nB) ? bsum[t] : 0;
    __syncthreads();
    for (int off = 1; off < 1024; off <<= 1) {
        int v = (t >= off) ? s[t - off] : 0;
        __syncthreads();
        s[t] += v;
        __syncthreads();
    }
    if (t < nB) bpre[t] = (t == 0) ? 0 : s[t - 1];
}

__global__ void k_scan_c(const int* __restrict__ degi, const int* __restrict__ bpre,
                         int* __restrict__ offs, int* __restrict__ cursor,
                         float* __restrict__ dinv, int n, int E) {
    __shared__ int s[256];
    int t = threadIdx.x;
    int base = blockIdx.x * SCB + t * 4;
    int d0 = 0, d1 = 0, d2 = 0, d3 = 0;
    if (base + 3 < n) {
        int4 v = *(const int4*)(degi + base);
        d0 = v.x; d1 = v.y; d2 = v.z; d3 = v.w;
    } else {
        if (base     < n) d0 = degi[base];
        if (base + 1 < n) d1 = degi[base + 1];
        if (base + 2 < n) d2 = degi[base + 2];
        if (base + 3 < n) d3 = degi[base + 3];
    }
    s[t] = d0 + d1 + d2 + d3;
    __syncthreads();
    for (int off = 1; off < 256; off <<= 1) {
        int v = (t >= off) ? s[t - off] : 0;
        __syncthreads();
        s[t] += v;
        __syncthreads();
    }
    int run = bpre[blockIdx.x] + ((t == 0) ? 0 : s[t - 1]);
    int o0 = run, o1 = o0 + d0, o2 = o1 + d1, o3 = o2 + d2;
    if (base < n)     { offs[base]   = o0; cursor[base]   = o0; dinv[base]   = rsqrtf((float)(d0 + 1)); }
    if (base + 1 < n) { offs[base+1] = o1; cursor[base+1] = o1; dinv[base+1] = rsqrtf((float)(d1 + 1)); }
    if (base + 2 < n) { offs[base+2] = o2; cursor[base+2] = o2; dinv[base+2] = rsqrtf((float)(d2 + 1)); }
    if (base + 3 < n) { offs[base+3] = o3; cursor[base+3] = o3; dinv[base+3] = rsqrtf((float)(d3 + 1)); }
    if (blockIdx.x == 0 && t == 0) offs[n] = E;
}

// ---------------- fused: counting-sort placement + dinv scale of xw1 ----------------
__global__ void k_sort_scale(const int* __restrict__ row, const int* __restrict__ col,
                             int* __restrict__ cursor, int* __restrict__ srow, int E,
                             int sBlocks, float* __restrict__ sxw,
                             const float* __restrict__ dinv, int n4) {
    if (blockIdx.x < sBlocks) {
        int e = blockIdx.x * TB + threadIdx.x;
        if (e >= E) return;
        int c = col[e];
        int pos = atomicAdd(&cursor[c], 1);
        srow[pos] = row[e];
        return;
    }
    int idx = (blockIdx.x - sBlocks) * TB + threadIdx.x;  // float4 index
    if (idx >= n4) return;
    float s = dinv[idx >> 2];
    float4* p = (float4*)sxw + idx;
    float4 v = *p;
    v.x *= s; v.y *= s; v.z *= s; v.w *= s;
    *p = v;
}

// ---------------- layer-1 gather: acc1[c] = sxw1[c] + sum_{r in in(c)} sxw1[r] ----------------
__global__ void k_gather1(const int* __restrict__ offs, const int* __restrict__ srow,
                          const float* __restrict__ sxw, float* __restrict__ acc, int n) {
    int idx  = blockIdx.x * TB + threadIdx.x;
    int node = idx >> 2, q = idx & 3;
    if (node >= n) return;
    const float4* s4 = (const float4*)sxw;
    int beg = offs[node], end = offs[node + 1];
    float4 a = s4[node * 4 + q];  // self-loop
    int j = beg;
    for (; j + 1 < end; j += 2) {
        int r0 = srow[j], r1 = srow[j + 1];
        float4 v0 = s4[r0 * 4 + q];
        float4 v1 = s4[r1 * 4 + q];
        a.x += v0.x + v1.x; a.y += v0.y + v1.y;
        a.z += v0.z + v1.z; a.w += v0.w + v1.w;
    }
    if (j < end) {
        int r0 = srow[j];
        float4 v0 = s4[r0 * 4 + q];
        a.x += v0.x; a.y += v0.y; a.z += v0.z; a.w += v0.w;
    }
    ((float4*)acc)[node * 4 + q] = a;
}

// ---------------- finalize layer 1 + layer-2 GEMM -> sxw2 padded to [N,8] ----------------
__global__ void k_fin1(const float* __restrict__ acc1, const float* __restrict__ dinv,
                       const float* __restrict__ W2, const float* __restrict__ b1,
                       float* __restrict__ sxw2p, int n) {
    __shared__ float sW2[112];
    __shared__ float sb1[16];
    if (threadIdx.x < 112) sW2[threadIdx.x] = W2[threadIdx.x];
    if (threadIdx.x < 16) sb1[threadIdx.x] = b1[threadIdx.x];
    __syncthreads();

    int i = blockIdx.x * TB + threadIdx.x;
    if (i >= n) return;
    float s = dinv[i];

    float h[16];
    const float4* a4 = (const float4*)(acc1 + (size_t)i * 16);
#pragma unroll
    for (int q = 0; q < 4; ++q) {
        float4 v = a4[q];
        h[4 * q + 0] = fmaxf(fmaf(s, v.x, sb1[4 * q + 0]), 0.f);
        h[4 * q + 1] = fmaxf(fmaf(s, v.y, sb1[4 * q + 1]), 0.f);
        h[4 * q + 2] = fmaxf(fmaf(s, v.z, sb1[4 * q + 2]), 0.f);
        h[4 * q + 3] = fmaxf(fmaf(s, v.w, sb1[4 * q + 3]), 0.f);
    }
    float o[8] = {0.f, 0.f, 0.f, 0.f, 0.f, 0.f, 0.f, 0.f};
#pragma unroll
    for (int k = 0; k < 16; ++k) {
        float hk = h[k];
#pragma unroll
        for (int j = 0; j < 7; ++j) o[j] = fmaf(hk, sW2[k * 7 + j], o[j]);
    }
    float4* dst = (float4*)(sxw2p + (size_t)i * 8);
    float4 lo, hi;
    lo.x = o[0] * s; lo.y = o[1] * s; lo.z = o[2] * s; lo.w = o[3] * s;
    hi.x = o[4] * s; hi.y = o[5] * s; hi.z = o[6] * s; hi.w = 0.f;
    dst[0] = lo; dst[1] = hi;
}

// ---------------- layer-2 gather on padded [N,8]: 2 lanes per node ----------------
__global__ void k_gather2(const int* __restrict__ offs, const int* __restrict__ srow,
                          const float* __restrict__ sxw2p, float* __restrict__ acc2p, int n) {
    int idx  = blockIdx.x * TB + threadIdx.x;
    int node = idx >> 1, q = idx & 1;
    if (node >= n) return;
    const float4* s4 = (const float4*)sxw2p;
    int beg = offs[node], end = offs[node + 1];
    float4 a = s4[node * 2 + q];  // self-loop
    int j = beg;
    for (; j + 1 < end; j += 2) {
        int r0 = srow[j], r1 = srow[j + 1];
        float4 v0 = s4[r0 * 2 + q];
        float4 v1 = s4[r1 * 2 + q];
        a.x += v0.x + v1.x; a.y += v0.y + v1.y;
        a.z += v0.z + v1.z; a.w += v0.w + v1.w;
    }
    if (j < end) {
        int r0 = srow[j];
        float4 v0 = s4[r0 * 2 + q];
        a.x += v0.x; a.y += v0.y; a.z += v0.z; a.w += v0.w;
    }
    ((float4*)acc2p)[node * 2 + q] = a;
}

// ---------------- finalize layer 2 + log_softmax ----------------
__global__ void k_fin2(const float* __restrict__ acc2p, const float* __restrict__ dinv,
                       const float* __restrict__ b2, float* __restrict__ out, int n) {
    int i = blockIdx.x * TB + threadIdx.x;
    if (i >= n) return;
    float s = dinv[i];
    const float* a = acc2p + (size_t)i * 8;
    float z[7];
    float m = -INFINITY;
#pragma unroll
    for (int j = 0; j < 7; ++j) {
        z[j] = fmaf(s, a[j], b2[j]);
        m = fmaxf(m, z[j]);
    }
    float sum = 0.f;
#pragma unroll
    for (int j = 0; j < 7; ++j) sum += expf(z[j] - m);
    float l = m + logf(sum);
    size_t base = (size_t)i * 7;
#pragma unroll
    for (int j = 0; j < 7; ++j) out[base + j] = z[j] - l;
}

extern "C" void kernel_launch(void* const* d_in, const int* in_sizes, int n_in,
                              void* d_out, int out_size, void* d_ws, size_t ws_size,
                              hipStream_t stream) {
    const float* x  = (const float*)d_in[0];
    const int*   ei = (const int*)d_in[1];
    const float* W1 = (const float*)d_in[2];
    const float* b1 = (const float*)d_in[3];
    const float* W2 = (const float*)d_in[4];
    const float* b2 = (const float*)d_in[5];

    int N = in_sizes[0] / 512;  // 100000
    int E = in_sizes[1] / 2;    // 3200000
    const int* row = ei;        // sources
    const int* col = ei + E;    // targets

    // workspace layout
    int* degi   = (int*)d_ws;          // N
    int* offs   = degi + N;            // N+1
    int* cursor = offs + N + 1;        // N
    int* bsum   = cursor + N;          // 128
    int* bpre   = bsum + 128;          // 128
    int* srow   = bpre + 128;          // E
    uintptr_t p = (uintptr_t)(srow + E);
    p = (p + 15) & ~(uintptr_t)15;
    float* dinv  = (float*)p;                 // N
    float* sxw1  = dinv + N;                  // 16N (unscaled xw1, scaled in place)
    float* acc1  = sxw1 + (size_t)16 * N;     // 16N
    float* sxw2p = sxw1;                      // 8N, aliases dead sxw1
    float* acc2p = acc1;                      // 8N, aliases dead acc1
    float* out   = (float*)d_out;

    int gN  = (N + TB - 1) / TB;
    int gE  = (E + TB - 1) / TB;
    int gG  = (4 * N + TB - 1) / TB;   // gemm / scale / gather1 blocks
    int nB  = (N + SCB - 1) / SCB;     // scan blocks (98)

    k_zero      <<<gN, TB, 0, stream>>>(degi, N);
    k_count_gemm<<<gE + gG, TB, 0, stream>>>(col, degi, E, gE, x, W1, sxw1, N);
    k_scan_a    <<<nB, 256, 0, stream>>>(degi, bsum, N);
    k_scan_b    <<<1, 1024, 0, stream>>>(bsum, bpre, nB);
    k_scan_c    <<<nB, 256, 0, stream>>>(degi, bpre, offs, cursor, dinv, N, E);
    k_sort_scale<<<gE + gG, TB, 0, stream>>>(row, col, cursor, srow, E, gE, sxw1, dinv, 4 * N);
    k_gather1   <<<gG, TB, 0, stream>>>(offs, srow, sxw1, acc1, N);
    k_fin1      <<<gN, TB, 0, stream>>>(acc1, dinv, W2, b1, sxw2p, N);
    k_gather2   <<<(2 * N + TB - 1) / TB, TB, 0, stream>>>(offs, srow, sxw2p, acc2p, N);
    k_fin2      <<<gN, TB, 0, stream>>>(acc2p, dinv, b2, out, N);
}